// Round 18
// baseline (126.380 us; speedup 1.0000x reference)
//
#include <hip/hip_runtime.h>

using US   = unsigned short;
using bf8  = __attribute__((ext_vector_type(8))) __bf16;
using us8  = __attribute__((ext_vector_type(8))) US;
using us4  = __attribute__((ext_vector_type(4))) US;
using f4   = __attribute__((ext_vector_type(4))) float;
using f8   = __attribute__((ext_vector_type(8))) float;
using f16v = __attribute__((ext_vector_type(16))) float;
using i4   = __attribute__((ext_vector_type(4))) int;
using u2   = __attribute__((ext_vector_type(2))) unsigned;

__device__ __forceinline__ US f2bf(float x) {
  union { float f; unsigned u; } v; v.f = x;
  unsigned r = v.u + 0x7fffu + ((v.u >> 16) & 1u);
  return (US)(r >> 16);
}
__device__ __forceinline__ unsigned cvtpk(float a, float b) {
  unsigned r;
  asm("v_cvt_pk_bf16_f32 %0, %1, %2" : "=v"(r) : "v"(a), "v"(b));
  return r;
}
// raw v_exp_f32 (exp2): avoids the denormal-guard expansion of libm exp2f
#if __has_builtin(__builtin_amdgcn_exp2f)
__device__ __forceinline__ float ex2(float x) { return __builtin_amdgcn_exp2f(x); }
#else
__device__ __forceinline__ float ex2(float x) {
  float r;
  asm("v_exp_f32 %0, %1" : "=v"(r) : "v"(x));
  return r;
}
#endif
// async global->LDS, 16B/lane, linear LDS dest (wave-uniform base + lane*16)
__device__ __forceinline__ void gl16(const US* g, US* l) {
  __builtin_amdgcn_global_load_lds((const __attribute__((address_space(1))) void*)g,
                                   (__attribute__((address_space(3))) void*)l, 16, 0, 0);
}

// ---------- fp32 -> bf16 elementwise, 8 elems/lane ----------
__global__ void cvt_k(const float* __restrict__ in, US* __restrict__ out, int n8) {
  int i = blockIdx.x * blockDim.x + threadIdx.x;
  if (i >= n8) return;
  f8 v = ((const f8*)in)[i];
  us8 o;
#pragma unroll
  for (int j = 0; j < 8; ++j) o[j] = f2bf(v[j]);
  ((us8*)out)[i] = o;
}

// ---------- fp32 (R x C) -> bf16 (C x R) transpose ----------
__global__ void trw_k(const float* __restrict__ in, US* __restrict__ out, int R, int C) {
  __shared__ float tile[32][33];
  int bx = blockIdx.x * 32, by = blockIdx.y * 32;
  int tx = threadIdx.x & 31, ty = threadIdx.x >> 5;
  for (int i = ty; i < 32; i += 8)
    tile[i][tx] = in[(size_t)(by + i) * C + bx + tx];
  __syncthreads();
  for (int i = ty; i < 32; i += 8)
    out[(size_t)(bx + i) * R + by + tx] = f2bf(tile[tx][i]);
}

// 2-bit+2-bit XOR swizzle for BK=32 tiles: spreads 16B units so frag reads are
// 2-way (free) instead of 4-way. SW depends only on row&15.
__device__ __forceinline__ int SW4(int row) { return (row & 3) ^ ((row >> 2) & 3); }

// ---------- C[M,N] = A[M,K](bf16) * Bt[N,K](bf16)^T + bias(f32) ----------
// (frozen r16 version) counted-vmcnt protocol: BK=32, triple-buffered gl16
// staging, vmcnt(4) counted waits, ONE barrier per K-step.
template <typename OT, bool QSC = false, bool VT = false>
__global__ __launch_bounds__(256, 2) void gemm_ct(const US* __restrict__ A,
                                                  const US* __restrict__ Bt,
                                                  const float* __restrict__ bias,
                                                  OT* __restrict__ out,
                                                  US* __restrict__ vtout,
                                                  int M, int N, int K) {
  __shared__ US lA[3][128 * 32];        // 3 x 8 KB
  __shared__ US lB[3][128 * 32];        // 3 x 8 KB
  const int t = threadIdx.x;
  const int lane = t & 63;
  const int w = t >> 6;
  const int wr = w >> 1, wc = w & 1;
  const int l15 = lane & 15, g = lane >> 4;
  const int m0 = blockIdx.x * 128, n0 = blockIdx.y * 128;

  float bv[4];
#pragma unroll
  for (int ni = 0; ni < 4; ++ni)
    bv[ni] = bias ? bias[n0 + wc * 64 + ni * 16 + l15] : 0.0f;

  const int r16 = lane >> 2;
  const int u4 = lane & 3;
  const int csw = (u4 ^ SW4(r16)) * 8;

#define GSTAGE(buf, k0s)                                                          \
  {                                                                               \
    _Pragma("unroll") for (int s = 0; s < 2; ++s) {                               \
      const int rb = w * 32 + s * 16;                                             \
      gl16(A + (size_t)(m0 + rb + r16) * K + (k0s) + csw, &lA[buf][rb * 32]);     \
      gl16(Bt + (size_t)(n0 + rb + r16) * K + (k0s) + csw, &lB[buf][rb * 32]);    \
    }                                                                             \
  }

  GSTAGE(0, 0);

  f4 acc[4][4] = {};
  const int kk = K >> 5;
  int cur = 0;
  for (int tt = 0; tt < kk; ++tt) {
    if (tt + 1 < kk) {
      int nb = cur + 1; if (nb == 3) nb = 0;
      GSTAGE(nb, (tt + 1) * 32);
      asm volatile("s_waitcnt vmcnt(4)" ::: "memory");
    } else {
      asm volatile("s_waitcnt vmcnt(0)" ::: "memory");
    }
    __builtin_amdgcn_s_barrier();
    asm volatile("" ::: "memory");

    const US* a_ = lA[cur];
    const US* b_ = lB[cur];
    bf8 af[4], bfr[4];
#pragma unroll
    for (int mi = 0; mi < 4; ++mi) {
      int row = wr * 64 + mi * 16 + l15;
      af[mi] = *(const bf8*)((const char*)a_ + row * 64 + ((g ^ SW4(row)) << 4));
    }
#pragma unroll
    for (int ni = 0; ni < 4; ++ni) {
      int row = wc * 64 + ni * 16 + l15;
      bfr[ni] = *(const bf8*)((const char*)b_ + row * 64 + ((g ^ SW4(row)) << 4));
    }
    __builtin_amdgcn_s_setprio(1);
#pragma unroll
    for (int mi = 0; mi < 4; ++mi)
#pragma unroll
      for (int ni = 0; ni < 4; ++ni)
        acc[mi][ni] = __builtin_amdgcn_mfma_f32_16x16x32_bf16(af[mi], bfr[ni], acc[mi][ni], 0, 0, 0);
    __builtin_amdgcn_s_setprio(0);
    cur = cur + 1 == 3 ? 0 : cur + 1;
  }
#undef GSTAGE

  if (VT && n0 >= 2048) {
#pragma unroll
    for (int ni = 0; ni < 4; ++ni) {
      int cv = n0 - 2048 + wc * 64 + ni * 16 + l15;
      int h2 = cv >> 6, d = cv & 63;
#pragma unroll
      for (int mi = 0; mi < 4; ++mi) {
        int rowb = m0 + wr * 64 + mi * 16 + g * 4;
        int bb = rowb >> 11, tloc = rowb & 2047;
        us4 pk;
#pragma unroll
        for (int r = 0; r < 4; ++r) pk[r] = f2bf(acc[mi][ni][r] + bv[ni]);
        *(us4*)(vtout + ((size_t)(bb * 16 + h2) * 64 + d) * 2048 + tloc) = pk;
      }
    }
    return;
  }
  const float oscale = (QSC && n0 < 1024) ? 0.18033688011f : 1.0f;
#pragma unroll
  for (int ni = 0; ni < 4; ++ni) {
    int col = n0 + wc * 64 + ni * 16 + l15;
#pragma unroll
    for (int mi = 0; mi < 4; ++mi) {
      int rowb = m0 + wr * 64 + mi * 16 + g * 4;
#pragma unroll
      for (int r = 0; r < 4; ++r) {
        float val = (acc[mi][ni][r] + bv[ni]) * oscale;
        if constexpr (sizeof(OT) == 2)
          out[(size_t)(rowb + r) * N + col] = f2bf(val);
        else
          out[(size_t)(rowb + r) * N + col] = val;
      }
    }
  }
}

// K frag read: row r (128B rows), 16B unit u: byte = r*128 + ((u^(r&7))<<4)
__device__ __forceinline__ const bf8* fragp(const US* base, int r, int u) {
  int byte = r * 128 + ((u ^ (r & 7)) << 4);
  return (const bf8*)((const char*)base + byte);
}
// V frag read: row r (64B rows), 16B unit u in [0,4): byte = r*64 + ((u^(r&3))<<4)
__device__ __forceinline__ const bf8* vfragp(const US* base, int r, int u) {
  int byte = r * 64 + ((u ^ (r & 3)) << 4);
  return (const bf8*)((const char*)base + byte);
}

// ---------- flash attention: split-KV x2 in-block, 12 waves/CU ----------
// Block = 4 waves over 64 q-rows x 2048 keys: wave (qh=w&1, kh=w>>1) owns
// 32 q-rows x keys [kh*1024,+1024) in 32 tiles of KVBLK=32. Grid 1024 blocks
// -> LDS 48.5 KB allows 3 blocks/CU = 12 waves/CU (the r17 grid-cap lesson:
// 512 blocks could never exceed 2/CU). Per-group triple-buffered K+V staged
// with the verified counted-vmcnt(4) gl16 protocol (4 gl16/wave/tile). No-max
// softmax -> split merge is exact plain sums via dead-lK overlay (r11 merge).
__global__ __launch_bounds__(256, 2) void attn_k(const US* __restrict__ qkv,
                                                 const US* __restrict__ vt,
                                                 const int* __restrict__ mask,
                                                 US* __restrict__ y) {
  int f0 = blockIdx.x;                  // 0..1023
  int f = ((f0 & 7) << 7) | (f0 >> 3);  // XCD bijective remap (1024 = 8*128)
  const int qt = f & 31;                // 32 q-tiles of 64 rows
  const int bh = f >> 5;                // 0..31
  const int b = bh >> 4;
  const int h = bh & 15;
  const int lane = threadIdx.x & 63, w = threadIdx.x >> 6;
  const int l31 = lane & 31, hi = lane >> 5;
  const int qh = w & 1, kh = w >> 1;

  __shared__ US lK[2][3][32 * 64];      // 2 groups x 3 bufs x 4 KB = 24 KB
  __shared__ US lV[2][3][64 * 32];      // 24 KB
  __shared__ unsigned char lMaskB[256]; // 2048 mask bits

  // Q fragments (B operand: col=q=l31, k-dim dh = ks*16 + hi*8 + i), resident
  const int qr0 = qt * 64 + qh * 32;
  const US* qrow = qkv + (size_t)(b * 2048 + qr0 + l31) * 3072 + h * 64 + hi * 8;
  bf8 qf[4];
#pragma unroll
  for (int ks = 0; ks < 4; ++ks) qf[ks] = *(const bf8*)(qrow + ks * 16);

  // K staging (rows=keys, 128B rows): wave stages rows [qh*16,+16) of the tile
  const int r8 = lane >> 3;
  const int c16 = (lane & 7) ^ r8;
  const US* kg = qkv + (size_t)b * 2048 * 3072 + 1024 + h * 64 + c16 * 8;
  // V staging (rows=d, 64B rows): wave stages d-rows [qh*32,+32)
  const int vr16 = lane >> 2;
  const int vc4 = (lane & 3) ^ (vr16 & 3);
  const US* vg = vt + (size_t)bh * 64 * 2048 + vc4 * 8;
  const int kv0 = kh * 1024;

  f16v o0 = {}, o1 = {};                // O^T: col=q=l31, rows d (+32 for o1)
  f16v osum = {};                       // ones-MFMA row-sum accumulator
  bf8 ones;
  {
    union { US u[8]; bf8 v; } on;
#pragma unroll
    for (int i = 0; i < 8; ++i) on.u[i] = 0x3F80;
    ones = on.v;
  }

#define STAGE(buf, j0s)                                                          \
  {                                                                              \
    gl16(kg + (size_t)((j0s) + qh * 16 + r8) * 3072, &lK[kh][buf][(qh * 16) * 64]); \
    gl16(kg + (size_t)((j0s) + qh * 16 + 8 + r8) * 3072, &lK[kh][buf][(qh * 16 + 8) * 64]); \
    gl16(vg + (size_t)(qh * 32 + vr16) * 2048 + (j0s), &lV[kh][buf][(qh * 32) * 32]); \
    gl16(vg + (size_t)(qh * 32 + 16 + vr16) * 2048 + (j0s), &lV[kh][buf][(qh * 32 + 16) * 32]); \
  }

  STAGE(0, kv0);                        // 4 loads in flight

  // prologue: mask -> 256B LDS bitmask + block-uniform all-ones fast-path flag
  int allones;
  {
    const int t8 = threadIdx.x * 8;
    i4 ma = *(const i4*)(mask + b * 2048 + t8);
    i4 mc = *(const i4*)(mask + b * 2048 + t8 + 4);
    unsigned byte = 0;
#pragma unroll
    for (int k = 0; k < 4; ++k) {
      byte |= (ma[k] != 0 ? 1u : 0u) << k;
      byte |= (mc[k] != 0 ? 1u : 0u) << (k + 4);
    }
    lMaskB[threadIdx.x] = (unsigned char)byte;
    allones = __syncthreads_and((int)(byte == 0xFFu));
  }

#define ATILE(tt, CUR, NXT, LAST)                                              \
  {                                                                            \
    const int j0_ = kv0 + (tt) * 32;                                           \
    if (!(LAST)) {                                                             \
      STAGE(NXT, j0_ + 32);                                                    \
      asm volatile("s_waitcnt vmcnt(4)" ::: "memory");                         \
    } else {                                                                   \
      asm volatile("s_waitcnt vmcnt(0)" ::: "memory");                         \
    }                                                                          \
    __builtin_amdgcn_s_barrier();                                              \
    asm volatile("" ::: "memory");                                             \
    const US* lKc = lK[kh][CUR];                                               \
    const US* lVc = lV[kh][CUR];                                               \
    f16v s0 = {};                                                              \
    __builtin_amdgcn_s_setprio(1);                                             \
    _Pragma("unroll") for (int ks = 0; ks < 4; ++ks) {                         \
      bf8 ka0 = *fragp(lKc, l31, 2 * ks + hi);                                 \
      s0 = __builtin_amdgcn_mfma_f32_32x32x16_bf16(ka0, qf[ks], s0, 0, 0, 0);  \
    }                                                                          \
    __builtin_amdgcn_s_setprio(0);                                             \
    _Pragma("unroll") for (int i = 0; i < 16; ++i) s0[i] = ex2(s0[i]);         \
    if (!allones) {                                                            \
      unsigned mbits = *(const unsigned*)&lMaskB[j0_ >> 3];                    \
      _Pragma("unroll") for (int i = 0; i < 16; ++i) {                         \
        int r = (i & 3) + 8 * (i >> 2) + 4 * hi;                               \
        if (!((mbits >> r) & 1)) s0[i] = 0.0f;                                 \
      }                                                                        \
    }                                                                          \
    bf8 pf[2];                                                                 \
    _Pragma("unroll") for (int ks = 0; ks < 2; ++ks) {                         \
      const int R = ks * 8;                                                    \
      unsigned w0 = cvtpk(s0[R + 0], s0[R + 1]);                               \
      unsigned w1 = cvtpk(s0[R + 2], s0[R + 3]);                               \
      unsigned w2 = cvtpk(s0[R + 4], s0[R + 5]);                               \
      unsigned w3 = cvtpk(s0[R + 6], s0[R + 7]);                               \
      u2 p02 = __builtin_amdgcn_permlane32_swap(w0, w2, false, false);         \
      u2 p13 = __builtin_amdgcn_permlane32_swap(w1, w3, false, false);         \
      union { unsigned u[4]; bf8 v; } bld;                                     \
      bld.u[0] = p02[0];                                                       \
      bld.u[1] = p13[0];                                                       \
      bld.u[2] = p02[1];                                                       \
      bld.u[3] = p13[1];                                                       \
      pf[ks] = bld.v;                                                          \
    }                                                                          \
    __builtin_amdgcn_s_setprio(1);                                             \
    _Pragma("unroll") for (int ks = 0; ks < 2; ++ks) {                         \
      bf8 vf0 = *vfragp(lVc, l31, 2 * ks + hi);                                \
      bf8 vf1 = *vfragp(lVc, 32 + l31, 2 * ks + hi);                           \
      o0 = __builtin_amdgcn_mfma_f32_32x32x16_bf16(vf0, pf[ks], o0, 0, 0, 0);  \
      o1 = __builtin_amdgcn_mfma_f32_32x32x16_bf16(vf1, pf[ks], o1, 0, 0, 0);  \
      osum = __builtin_amdgcn_mfma_f32_32x32x16_bf16(ones, pf[ks], osum, 0, 0, 0); \
    }                                                                          \
    __builtin_amdgcn_s_setprio(0);                                             \
  }

  for (int gg = 0; gg < 10; ++gg) {
    const int t3 = gg * 3;
    ATILE(t3, 0, 1, 0)
    ATILE(t3 + 1, 1, 2, 0)
    ATILE(t3 + 2, 2, 0, 0)
  }
  ATILE(30, 0, 1, 0)
  ATILE(31, 1, 2, 1)
#undef ATILE
#undef STAGE

  // ---- split-KV merge: exact sums (no max baseline) via dead-lK overlay ----
  __syncthreads();                      // all LDS K/V reads complete everywhere
  float* xch = (float*)&lK[0][0][0];    // 2 x 64 lanes x 34 floats = 17.4 KB
  const int xi = (qh * 64 + lane) * 34;
  if (kh) {
#pragma unroll
    for (int i = 0; i < 16; ++i) xch[xi + i] = o0[i];
#pragma unroll
    for (int i = 0; i < 16; ++i) xch[xi + 16 + i] = o1[i];
    xch[xi + 32] = osum[0];
  }
  __syncthreads();
  if (!kh) {
    float inv = 1.0f / (osum[0] + xch[xi + 32]);
    US* yrow = y + (size_t)(b * 2048 + qr0 + l31) * 1024 + h * 64;
#pragma unroll
    for (int qd = 0; qd < 4; ++qd) {
      us4 pk0, pk1;
#pragma unroll
      for (int j = 0; j < 4; ++j) {
        int i = qd * 4 + j;
        pk0[j] = f2bf((o0[i] + xch[xi + i]) * inv);
        pk1[j] = f2bf((o1[i] + xch[xi + 16 + i]) * inv);
      }
      *(us4*)(yrow + qd * 8 + hi * 4) = pk0;
      *(us4*)(yrow + 32 + qd * 8 + hi * 4) = pk1;
    }
  }
}

extern "C" void kernel_launch(void* const* d_in, const int* in_sizes, int n_in,
                              void* d_out, int out_size, void* d_ws, size_t ws_size,
                              hipStream_t stream) {
  const float* x     = (const float*)d_in[0];
  const int*   mask  = (const int*)d_in[1];
  const float* Wqkv  = (const float*)d_in[2];
  const float* bqkv  = (const float*)d_in[3];
  const float* Wproj = (const float*)d_in[4];
  const float* bproj = (const float*)d_in[5];
  float* out = (float*)d_out;

  US* xb     = (US*)d_ws;                        // 4096*1024
  US* qkvb   = xb     + (size_t)4096 * 1024;     // 4096*3072 (V region unused)
  US* WqkvT  = qkvb   + (size_t)4096 * 3072;     // 3072*1024
  US* WprojT = WqkvT  + (size_t)3072 * 1024;     // 1024*1024
  US* Vt     = WprojT + (size_t)1024 * 1024;     // 32*64*2048
  US* yb     = Vt     + (size_t)32 * 64 * 2048;  // 4096*1024

  cvt_k<<<2048, 256, 0, stream>>>(x, xb, 4096 * 1024 / 8);
  trw_k<<<dim3(96, 32), 256, 0, stream>>>(Wqkv, WqkvT, 1024, 3072);
  trw_k<<<dim3(32, 32), 256, 0, stream>>>(Wproj, WprojT, 1024, 1024);
  gemm_ct<US, true, true><<<dim3(32, 24), 256, 0, stream>>>(xb, WqkvT, bqkv, qkvb, Vt, 4096, 3072, 1024);
  attn_k<<<1024, 256, 0, stream>>>(qkvb, Vt, mask, yb);
  gemm_ct<float><<<dim3(32, 8), 256, 0, stream>>>(yb, WprojT, bproj, out, nullptr, 4096, 1024, 1024);
}

// Round 19
// 111.856 us; speedup vs baseline: 1.1298x; 1.1298x over previous
//
#include <hip/hip_runtime.h>

using US   = unsigned short;
using bf8  = __attribute__((ext_vector_type(8))) __bf16;
using us8  = __attribute__((ext_vector_type(8))) US;
using us4  = __attribute__((ext_vector_type(4))) US;
using f4   = __attribute__((ext_vector_type(4))) float;
using f8   = __attribute__((ext_vector_type(8))) float;
using f16v = __attribute__((ext_vector_type(16))) float;
using i4   = __attribute__((ext_vector_type(4))) int;
using u2   = __attribute__((ext_vector_type(2))) unsigned;

__device__ __forceinline__ US f2bf(float x) {
  union { float f; unsigned u; } v; v.f = x;
  unsigned r = v.u + 0x7fffu + ((v.u >> 16) & 1u);
  return (US)(r >> 16);
}
__device__ __forceinline__ unsigned cvtpk(float a, float b) {
  unsigned r;
  asm("v_cvt_pk_bf16_f32 %0, %1, %2" : "=v"(r) : "v"(a), "v"(b));
  return r;
}
// raw v_exp_f32 (exp2): avoids the denormal-guard expansion of libm exp2f
#if __has_builtin(__builtin_amdgcn_exp2f)
__device__ __forceinline__ float ex2(float x) { return __builtin_amdgcn_exp2f(x); }
#else
__device__ __forceinline__ float ex2(float x) {
  float r;
  asm("v_exp_f32 %0, %1" : "=v"(r) : "v"(x));
  return r;
}
#endif
// async global->LDS, 16B/lane, linear LDS dest (wave-uniform base + lane*16)
__device__ __forceinline__ void gl16(const US* g, US* l) {
  __builtin_amdgcn_global_load_lds((const __attribute__((address_space(1))) void*)g,
                                   (__attribute__((address_space(3))) void*)l, 16, 0, 0);
}

// ---------- fused prologue: cvt(x) + transpose(Wqkv) + transpose(Wproj) -------
// One dispatch, role by block range; each block runs exactly one role so the
// transpose __syncthreads stays block-uniform. Roles co-schedule across CUs.
__global__ void prep_k(const float* __restrict__ x, US* __restrict__ xb,
                       const float* __restrict__ Wqkv, US* __restrict__ WqkvT,
                       const float* __restrict__ Wproj, US* __restrict__ WprojT) {
  __shared__ float tile[32][33];
  int bid = blockIdx.x;
  if (bid < 2048) {                     // cvt: x fp32 -> bf16, 8 elems/lane
    int i = bid * 256 + threadIdx.x;
    f8 v = ((const f8*)x)[i];
    us8 o;
#pragma unroll
    for (int j = 0; j < 8; ++j) o[j] = f2bf(v[j]);
    ((us8*)xb)[i] = o;
    return;
  }
  const float* in;
  US* out;
  int R, C, tx0, ty0;
  if (bid < 2048 + 3072) {              // Wqkv^T: (1024 x 3072) -> (3072 x 1024)
    int tid = bid - 2048;
    in = Wqkv; out = WqkvT; R = 1024; C = 3072;
    tx0 = (tid % 96) * 32; ty0 = (tid / 96) * 32;
  } else {                              // Wproj^T: (1024 x 1024) -> (1024 x 1024)
    int tid = bid - 2048 - 3072;
    in = Wproj; out = WprojT; R = 1024; C = 1024;
    tx0 = (tid % 32) * 32; ty0 = (tid / 32) * 32;
  }
  int tx = threadIdx.x & 31, ty = threadIdx.x >> 5;
  for (int i = ty; i < 32; i += 8)
    tile[i][tx] = in[(size_t)(ty0 + i) * C + tx0 + tx];
  __syncthreads();
  for (int i = ty; i < 32; i += 8)
    out[(size_t)(tx0 + i) * R + ty0 + tx] = f2bf(tile[tx][i]);
}

// 2-bit+2-bit XOR swizzle for BK=32 tiles: spreads 16B units so frag reads are
// 2-way (free) instead of 4-way. SW depends only on row&15.
__device__ __forceinline__ int SW4(int row) { return (row & 3) ^ ((row >> 2) & 3); }

// ---------- C[M,N] = A[M,K](bf16) * Bt[N,K](bf16)^T + bias(f32) ----------
// (frozen r16 version) counted-vmcnt protocol: BK=32, triple-buffered gl16
// staging, vmcnt(4) counted waits, ONE barrier per K-step.
template <typename OT, bool QSC = false, bool VT = false>
__global__ __launch_bounds__(256, 2) void gemm_ct(const US* __restrict__ A,
                                                  const US* __restrict__ Bt,
                                                  const float* __restrict__ bias,
                                                  OT* __restrict__ out,
                                                  US* __restrict__ vtout,
                                                  int M, int N, int K) {
  __shared__ US lA[3][128 * 32];        // 3 x 8 KB
  __shared__ US lB[3][128 * 32];        // 3 x 8 KB
  const int t = threadIdx.x;
  const int lane = t & 63;
  const int w = t >> 6;
  const int wr = w >> 1, wc = w & 1;
  const int l15 = lane & 15, g = lane >> 4;
  const int m0 = blockIdx.x * 128, n0 = blockIdx.y * 128;

  float bv[4];
#pragma unroll
  for (int ni = 0; ni < 4; ++ni)
    bv[ni] = bias ? bias[n0 + wc * 64 + ni * 16 + l15] : 0.0f;

  const int r16 = lane >> 2;
  const int u4 = lane & 3;
  const int csw = (u4 ^ SW4(r16)) * 8;

#define GSTAGE(buf, k0s)                                                          \
  {                                                                               \
    _Pragma("unroll") for (int s = 0; s < 2; ++s) {                               \
      const int rb = w * 32 + s * 16;                                             \
      gl16(A + (size_t)(m0 + rb + r16) * K + (k0s) + csw, &lA[buf][rb * 32]);     \
      gl16(Bt + (size_t)(n0 + rb + r16) * K + (k0s) + csw, &lB[buf][rb * 32]);    \
    }                                                                             \
  }

  GSTAGE(0, 0);

  f4 acc[4][4] = {};
  const int kk = K >> 5;
  int cur = 0;
  for (int tt = 0; tt < kk; ++tt) {
    if (tt + 1 < kk) {
      int nb = cur + 1; if (nb == 3) nb = 0;
      GSTAGE(nb, (tt + 1) * 32);
      asm volatile("s_waitcnt vmcnt(4)" ::: "memory");
    } else {
      asm volatile("s_waitcnt vmcnt(0)" ::: "memory");
    }
    __builtin_amdgcn_s_barrier();
    asm volatile("" ::: "memory");

    const US* a_ = lA[cur];
    const US* b_ = lB[cur];
    bf8 af[4], bfr[4];
#pragma unroll
    for (int mi = 0; mi < 4; ++mi) {
      int row = wr * 64 + mi * 16 + l15;
      af[mi] = *(const bf8*)((const char*)a_ + row * 64 + ((g ^ SW4(row)) << 4));
    }
#pragma unroll
    for (int ni = 0; ni < 4; ++ni) {
      int row = wc * 64 + ni * 16 + l15;
      bfr[ni] = *(const bf8*)((const char*)b_ + row * 64 + ((g ^ SW4(row)) << 4));
    }
    __builtin_amdgcn_s_setprio(1);
#pragma unroll
    for (int mi = 0; mi < 4; ++mi)
#pragma unroll
      for (int ni = 0; ni < 4; ++ni)
        acc[mi][ni] = __builtin_amdgcn_mfma_f32_16x16x32_bf16(af[mi], bfr[ni], acc[mi][ni], 0, 0, 0);
    __builtin_amdgcn_s_setprio(0);
    cur = cur + 1 == 3 ? 0 : cur + 1;
  }
#undef GSTAGE

  if (VT && n0 >= 2048) {
#pragma unroll
    for (int ni = 0; ni < 4; ++ni) {
      int cv = n0 - 2048 + wc * 64 + ni * 16 + l15;
      int h2 = cv >> 6, d = cv & 63;
#pragma unroll
      for (int mi = 0; mi < 4; ++mi) {
        int rowb = m0 + wr * 64 + mi * 16 + g * 4;
        int bb = rowb >> 11, tloc = rowb & 2047;
        us4 pk;
#pragma unroll
        for (int r = 0; r < 4; ++r) pk[r] = f2bf(acc[mi][ni][r] + bv[ni]);
        *(us4*)(vtout + ((size_t)(bb * 16 + h2) * 64 + d) * 2048 + tloc) = pk;
      }
    }
    return;
  }
  const float oscale = (QSC && n0 < 1024) ? 0.18033688011f : 1.0f;
#pragma unroll
  for (int ni = 0; ni < 4; ++ni) {
    int col = n0 + wc * 64 + ni * 16 + l15;
#pragma unroll
    for (int mi = 0; mi < 4; ++mi) {
      int rowb = m0 + wr * 64 + mi * 16 + g * 4;
#pragma unroll
      for (int r = 0; r < 4; ++r) {
        float val = (acc[mi][ni][r] + bv[ni]) * oscale;
        if constexpr (sizeof(OT) == 2)
          out[(size_t)(rowb + r) * N + col] = f2bf(val);
        else
          out[(size_t)(rowb + r) * N + col] = val;
      }
    }
  }
}

// swizzled LDS fragment read: row r, 16B unit u = 2*ks+hi, byte = r*128 + ((u^(r&7))<<4)
__device__ __forceinline__ const bf8* fragp(const US* base, int r, int ks, int hi) {
  int byte = r * 128 + ((((ks << 1) | hi) ^ (r & 7)) << 4);
  return (const bf8*)((const char*)base + byte);
}

// ---------- flash attention: 4 waves x 32 q-rows, K/V quad-buffer, T15 pipe ----
// (frozen r16 version, 48.2 us verified) Counted vmcnt(4), pure-gl16 vmcnt
// domain, mask = 256B LDS bitmask + all-ones fast path, Q pre-scaled in qkv
// GEMM, raw v_exp_f32, ones-MFMA row-sum, x4-unrolled loop.
__global__ __launch_bounds__(256, 2) void attn_k(const US* __restrict__ qkv,
                                                 const US* __restrict__ vt,
                                                 const int* __restrict__ mask,
                                                 US* __restrict__ y) {
  int f0 = blockIdx.x;                  // 0..511
  int f = ((f0 & 7) << 6) | (f0 >> 3);  // XCD bijective remap (512 = 8*64): 4 heads/XCD
  const int qt = f & 15;                // 16 q-tiles of 128 rows
  const int bh = f >> 4;                // 0..31
  const int b = bh >> 4;
  const int h = bh & 15;
  const int lane = threadIdx.x & 63, w = threadIdx.x >> 6;
  const int l31 = lane & 31, hi = lane >> 5;

  __shared__ US lK[4][64 * 64];         // 32 KB
  __shared__ US lV[4][64 * 64];         // 32 KB
  __shared__ unsigned char lMaskB[256]; // 2048 mask bits

  const int qr0 = qt * 128 + w * 32;
  const US* qrow = qkv + (size_t)(b * 2048 + qr0 + l31) * 3072 + h * 64 + hi * 8;
  bf8 qf[4];
#pragma unroll
  for (int ks = 0; ks < 4; ++ks) qf[ks] = *(const bf8*)(qrow + ks * 16);

  const int r8 = lane >> 3;
  const int c16 = (lane & 7) ^ r8;
  const US* kg = qkv + (size_t)b * 2048 * 3072 + 1024 + h * 64 + c16 * 8;
  const US* vg = vt + (size_t)bh * 64 * 2048 + c16 * 8;
  const int R0 = w * 16;

  f16v o0 = {}, o1 = {};
  f16v osum = {};
  bf8 pf[4] = {};
  bf8 ones;
  {
    union { US u[8]; bf8 v; } on;
#pragma unroll
    for (int i = 0; i < 8; ++i) on.u[i] = 0x3F80;
    ones = on.v;
  }

#define STAGE(buf, j0s)                                                        \
  {                                                                            \
    gl16(kg + (size_t)((j0s) + R0 + r8) * 3072, &lK[buf][R0 * 64]);            \
    gl16(kg + (size_t)((j0s) + R0 + 8 + r8) * 3072, &lK[buf][(R0 + 8) * 64]);  \
    gl16(vg + (size_t)(R0 + r8) * 2048 + (j0s), &lV[buf][R0 * 64]);            \
    gl16(vg + (size_t)(R0 + 8 + r8) * 2048 + (j0s), &lV[buf][(R0 + 8) * 64]);  \
  }

  STAGE(0, 0);

  int allones;
  {
    const int t8 = threadIdx.x * 8;
    i4 ma = *(const i4*)(mask + b * 2048 + t8);
    i4 mc = *(const i4*)(mask + b * 2048 + t8 + 4);
    unsigned byte = 0;
#pragma unroll
    for (int k = 0; k < 4; ++k) {
      byte |= (ma[k] != 0 ? 1u : 0u) << k;
      byte |= (mc[k] != 0 ? 1u : 0u) << (k + 4);
    }
    lMaskB[threadIdx.x] = (unsigned char)byte;
    allones = __syncthreads_and((int)(byte == 0xFFu));
  }

#pragma unroll 4
  for (int tt = 0; tt < 32; ++tt) {
    const int cur = tt & 3;
    const int j0 = tt * 64;
    if (tt < 31) {
      STAGE((tt + 1) & 3, j0 + 64);
      asm volatile("s_waitcnt vmcnt(4)" ::: "memory");
    } else {
      asm volatile("s_waitcnt vmcnt(0)" ::: "memory");
    }
    __builtin_amdgcn_s_barrier();
    asm volatile("" ::: "memory");

    const US* lKc = lK[cur];

    f16v s0 = {}, s1 = {};
    __builtin_amdgcn_s_setprio(1);
#pragma unroll
    for (int ks = 0; ks < 4; ++ks) {
      bf8 ka0 = *fragp(lKc, l31, ks, hi);
      bf8 ka1 = *fragp(lKc, 32 + l31, ks, hi);
      s0 = __builtin_amdgcn_mfma_f32_32x32x16_bf16(ka0, qf[ks], s0, 0, 0, 0);
      s1 = __builtin_amdgcn_mfma_f32_32x32x16_bf16(ka1, qf[ks], s1, 0, 0, 0);
    }
    if (tt) {
      const US* lVp = lV[(tt + 3) & 3];
#pragma unroll
      for (int ks = 0; ks < 4; ++ks) {
        bf8 vf0 = *fragp(lVp, l31, ks, hi);
        bf8 vf1 = *fragp(lVp, 32 + l31, ks, hi);
        o0 = __builtin_amdgcn_mfma_f32_32x32x16_bf16(vf0, pf[ks], o0, 0, 0, 0);
        o1 = __builtin_amdgcn_mfma_f32_32x32x16_bf16(vf1, pf[ks], o1, 0, 0, 0);
        osum = __builtin_amdgcn_mfma_f32_32x32x16_bf16(ones, pf[ks], osum, 0, 0, 0);
      }
    }
    __builtin_amdgcn_s_setprio(0);

#pragma unroll
    for (int i = 0; i < 16; ++i) {
      s0[i] = ex2(s0[i]);
      s1[i] = ex2(s1[i]);
    }
    if (!allones) {
      unsigned mbyte = lMaskB[(j0 >> 3) + (lane >> 3)];
      int mword = (mbyte >> (lane & 7)) & 1;
      unsigned long long mbits = __ballot(mword != 0);
#pragma unroll
      for (int i = 0; i < 16; ++i) {
        int r = (i & 3) + 8 * (i >> 2) + 4 * hi;
        if (!((mbits >> r) & 1)) s0[i] = 0.0f;
        if (!((mbits >> (32 + r)) & 1)) s1[i] = 0.0f;
      }
    }

#pragma unroll
    for (int ks = 0; ks < 4; ++ks) {
      const f16v& st = (ks < 2) ? s0 : s1;
      const int R = (ks & 1) * 8;
      unsigned w0 = cvtpk(st[R + 0], st[R + 1]);
      unsigned w1 = cvtpk(st[R + 2], st[R + 3]);
      unsigned w2 = cvtpk(st[R + 4], st[R + 5]);
      unsigned w3 = cvtpk(st[R + 6], st[R + 7]);
      u2 p02 = __builtin_amdgcn_permlane32_swap(w0, w2, false, false);
      u2 p13 = __builtin_amdgcn_permlane32_swap(w1, w3, false, false);
      union { unsigned u[4]; bf8 v; } bld;
      bld.u[0] = p02[0];
      bld.u[1] = p13[0];
      bld.u[2] = p02[1];
      bld.u[3] = p13[1];
      pf[ks] = bld.v;
    }
  }
#undef STAGE

  {
    const US* lVp = lV[3];
    __builtin_amdgcn_s_setprio(1);
#pragma unroll
    for (int ks = 0; ks < 4; ++ks) {
      bf8 vf0 = *fragp(lVp, l31, ks, hi);
      bf8 vf1 = *fragp(lVp, 32 + l31, ks, hi);
      o0 = __builtin_amdgcn_mfma_f32_32x32x16_bf16(vf0, pf[ks], o0, 0, 0, 0);
      o1 = __builtin_amdgcn_mfma_f32_32x32x16_bf16(vf1, pf[ks], o1, 0, 0, 0);
      osum = __builtin_amdgcn_mfma_f32_32x32x16_bf16(ones, pf[ks], osum, 0, 0, 0);
    }
    __builtin_amdgcn_s_setprio(0);
  }

  float inv = 1.0f / osum[0];
  US* yrow = y + (size_t)(b * 2048 + qr0 + l31) * 1024 + h * 64;
#pragma unroll
  for (int qd = 0; qd < 4; ++qd) {
    us4 pk0, pk1;
#pragma unroll
    for (int j = 0; j < 4; ++j) {
      pk0[j] = f2bf(o0[qd * 4 + j] * inv);
      pk1[j] = f2bf(o1[qd * 4 + j] * inv);
    }
    *(us4*)(yrow + qd * 8 + hi * 4) = pk0;
    *(us4*)(yrow + 32 + qd * 8 + hi * 4) = pk1;
  }
}

extern "C" void kernel_launch(void* const* d_in, const int* in_sizes, int n_in,
                              void* d_out, int out_size, void* d_ws, size_t ws_size,
                              hipStream_t stream) {
  const float* x     = (const float*)d_in[0];
  const int*   mask  = (const int*)d_in[1];
  const float* Wqkv  = (const float*)d_in[2];
  const float* bqkv  = (const float*)d_in[3];
  const float* Wproj = (const float*)d_in[4];
  const float* bproj = (const float*)d_in[5];
  float* out = (float*)d_out;

  US* xb     = (US*)d_ws;                        // 4096*1024
  US* qkvb   = xb     + (size_t)4096 * 1024;     // 4096*3072 (V region unused)
  US* WqkvT  = qkvb   + (size_t)4096 * 3072;     // 3072*1024
  US* WprojT = WqkvT  + (size_t)3072 * 1024;     // 1024*1024
  US* Vt     = WprojT + (size_t)1024 * 1024;     // 32*64*2048
  US* yb     = Vt     + (size_t)32 * 64 * 2048;  // 4096*1024

  prep_k<<<6144, 256, 0, stream>>>(x, xb, Wqkv, WqkvT, Wproj, WprojT);
  gemm_ct<US, true, true><<<dim3(32, 24), 256, 0, stream>>>(xb, WqkvT, bqkv, qkvb, Vt, 4096, 3072, 1024);
  attn_k<<<512, 256, 0, stream>>>(qkvb, Vt, mask, yb);
  gemm_ct<float><<<dim3(32, 8), 256, 0, stream>>>(yb, WprojT, bproj, out, nullptr, 4096, 1024, 1024);
}